// Round 1
// baseline (135.929 us; speedup 1.0000x reference)
//
#include <hip/hip_runtime.h>

#define NB   4      // batch
#define CO   16     // out channels
#define PH   7
#define PW   7
#define SR   2
#define HH   80
#define WW   80
#define NROI 512
#define NOUT (NROI*CO*PH*PW)

__global__ __launch_bounds__(256) void psroi_align_kernel(
    const float* __restrict__ feat,   // [B, CO*PH*PW, H, W]
    const float* __restrict__ rois,   // [N, 5]
    float* __restrict__ out)          // [N, CO, PH, PW]
{
    int idx = blockIdx.x * blockDim.x + threadIdx.x;
    if (idx >= NOUT) return;

    int j = idx % PW;
    int i = (idx / PW) % PH;
    int c = (idx / (PW * PH)) % CO;
    int n = idx / (PW * PH * CO);

    const float* r = rois + n * 5;
    float rb = r[0];
    float x1 = r[1] * (float)WW;
    float y1 = r[2] * (float)HH;
    float x2 = r[3] * (float)WW;
    float y2 = r[4] * (float)HH;
    int b = (int)rb;

    float roi_h = fmaxf(y2 - y1, 0.1f);
    float roi_w = fmaxf(x2 - x1, 0.1f);
    float bin_h = roi_h * (1.0f / PH);
    float bin_w = roi_w * (1.0f / PW);

    // position-sensitive plane: channel = c*PH*PW + i*PW + j
    const float* plane = feat + ((size_t)b * (CO * PH * PW) + (size_t)(c * PH * PW + i * PW + j)) * (HH * WW);

    float acc = 0.0f;
    #pragma unroll
    for (int sy = 0; sy < SR; ++sy) {
        float ys = y1 + (float)i * bin_h + ((float)sy + 0.5f) * bin_h / (float)SR;
        bool ymask = (ys >= -1.0f) && (ys <= (float)HH);
        float yc = fminf(fmaxf(ys, 0.0f), (float)(HH - 1));
        int   y0 = (int)floorf(yc);
        int   y1i = min(y0 + 1, HH - 1);
        float ly = yc - (float)y0;
        float hy = 1.0f - ly;

        #pragma unroll
        for (int sx = 0; sx < SR; ++sx) {
            float xs = x1 + (float)j * bin_w + ((float)sx + 0.5f) * bin_w / (float)SR;
            bool xmask = (xs >= -1.0f) && (xs <= (float)WW);
            float xc = fminf(fmaxf(xs, 0.0f), (float)(WW - 1));
            int   x0 = (int)floorf(xc);
            int   x1i = min(x0 + 1, WW - 1);
            float lx = xc - (float)x0;
            float hx = 1.0f - lx;

            float v00 = plane[y0  * WW + x0 ];
            float v01 = plane[y0  * WW + x1i];
            float v10 = plane[y1i * WW + x0 ];
            float v11 = plane[y1i * WW + x1i];

            float v = v00 * (hy * hx) + v01 * (hy * lx)
                    + v10 * (ly * hx) + v11 * (ly * lx);

            if (ymask && xmask) acc += v;
        }
    }

    out[idx] = acc * 0.25f;
}

extern "C" void kernel_launch(void* const* d_in, const int* in_sizes, int n_in,
                              void* d_out, int out_size, void* d_ws, size_t ws_size,
                              hipStream_t stream)
{
    const float* feat = (const float*)d_in[0];
    const float* rois = (const float*)d_in[1];
    float* out = (float*)d_out;

    int total = NOUT;
    int block = 256;
    int grid = (total + block - 1) / block;
    psroi_align_kernel<<<grid, block, 0, stream>>>(feat, rois, out);
}